// Round 13
// baseline (1236.133 us; speedup 1.0000x reference)
//
#include <hip/hip_runtime.h>
#include <math.h>
#include <type_traits>

typedef __bf16 bf16_t;
typedef bf16_t bf16x4 __attribute__((ext_vector_type(4)));
typedef bf16_t bf16x8 __attribute__((ext_vector_type(8)));
typedef float  f32x4  __attribute__((ext_vector_type(4)));

#define RMS_EPS 1e-6f

enum { EP_STORE = 0, EP_RESID = 1, EP_SPLIT = 2, EP_SILU = 3 };

template<int V> using IC = std::integral_constant<int, V>;

static __device__ __forceinline__ f32x4 mfma16(bf16x8 a, bf16x8 b, f32x4 c) {
    return __builtin_amdgcn_mfma_f32_16x16x32_bf16(a, b, c, 0, 0, 0);
}

#define GLDS(gp, lp) __builtin_amdgcn_global_load_lds( \
    (const __attribute__((address_space(1))) void*)(gp), \
    (__attribute__((address_space(3))) void*)(lp), 16, 0, 0)

// counted vector-memory wait (T4): leave N newest loads in flight.
template<int N> static __device__ __forceinline__ void vmwait() {
    if constexpr (N == 0)      asm volatile("s_waitcnt vmcnt(0)" ::: "memory");
    else if constexpr (N == 2) asm volatile("s_waitcnt vmcnt(2)" ::: "memory");
    else if constexpr (N == 3) asm volatile("s_waitcnt vmcnt(3)" ::: "memory");
    else if constexpr (N == 4) asm volatile("s_waitcnt vmcnt(4)" ::: "memory");
    else if constexpr (N == 6) asm volatile("s_waitcnt vmcnt(6)" ::: "memory");
    else if constexpr (N == 8) asm volatile("s_waitcnt vmcnt(8)" ::: "memory");
    __builtin_amdgcn_sched_barrier(0);
}
static __device__ __forceinline__ void bar() { __builtin_amdgcn_s_barrier(); }

// C[M,N] = A[M,K]*B[N,K]^T.
// PLANES==2: A split hi/lo, B hi-only (2 MFMAs).  PLANES==1: pure bf16.
// WR x WC wave grid (threads = WR*WC*64). Counted-vmcnt double-buffered K-loop.
// Requires (BM/16*planes + BN/16) % (WR*WC) == 0 so NLD is uniform per wave.
// EP_SILU: B is wGU interleaved; even lanes write silu(g)*u at col>>1.
// blockIdx.z = K-chunk for split-K.
template<int BM, int BN, int WR, int WC, int PLANES, int EPIL>
__global__ __launch_bounds__(WR * WC * 64,
    (WR * WC == 8) ? 4 : ((PLANES >= 2 && BM == 128) ? 3 : 4))
void gemm_bf16(const bf16_t* __restrict__ Ah, const bf16_t* __restrict__ Al,
               const bf16_t* __restrict__ Bh,
               float* __restrict__ Cf, bf16_t* __restrict__ Ch, bf16_t* __restrict__ Cl,
               int K, int lda, int ldb, int ldc, long long sC)
{
    constexpr int ASZ = BM * 32, BSZ = BN * 32;
    constexpr int NW = WR * WC;
    constexpr int NLD = (BM / 16 * (PLANES >= 2 ? 2 : 1) + BN / 16) / NW;
    __shared__ __align__(16) bf16_t sAh[2][ASZ], sBh[2][BSZ];
    __shared__ __align__(16) bf16_t sAl[PLANES >= 2 ? 2 : 1][PLANES >= 2 ? ASZ : 8];

    const int gx = gridDim.x;
    int id = blockIdx.x + gx * blockIdx.y;
    if (gridDim.z == 1) {  // bijective XCD swizzle (m204)
        int nwg = gx * gridDim.y;
        int q = nwg >> 3, r = nwg & 7;
        int xcd = id & 7, ix = id >> 3;
        id = (xcd < r ? xcd * (q + 1) : r * (q + 1) + (xcd - r) * q) + ix;
    }
    const int bm = id % gx, bn = id / gx;
    const int row0 = bm * BM, col0 = bn * BN;

    const size_t kofs = (size_t)blockIdx.z * K;
    Ah += kofs;  Bh += kofs;
    if constexpr (PLANES >= 2) Al += kofs;

    const int tid = threadIdx.x, lane = tid & 63, wave = tid >> 6;
    const int lr = lane & 15, lg = lane >> 4;
    constexpr int WM = BM / WR, WN = BN / WC, MF = WM / 16, NF = WN / 16;
    const int wr = wave / WC, wc = wave % WC;

    f32x4 acc[MF][NF];
    #pragma unroll
    for (int m = 0; m < MF; ++m)
        #pragma unroll
        for (int n = 0; n < NF; ++n) acc[m][n] = (f32x4){0.f, 0.f, 0.f, 0.f};

    auto stage = [&](int k0, auto pc) {
        constexpr int p = decltype(pc)::value;
        #pragma unroll
        for (int i = wave; i < BM / 16; i += NW) {
            int s = i * 64 + lane, rr = s >> 2, c = s & 3;
            size_t go = (size_t)(row0 + rr) * lda + k0 + ((c ^ ((rr >> 1) & 3)) << 3);
            GLDS(Ah + go, &sAh[p][i * 512]);
            if constexpr (PLANES >= 2) GLDS(Al + go, &sAl[p][i * 512]);
        }
        #pragma unroll
        for (int i = wave; i < BN / 16; i += NW) {
            int s = i * 64 + lane, rr = s >> 2, c = s & 3;
            size_t go = (size_t)(col0 + rr) * ldb + k0 + ((c ^ ((rr >> 1) & 3)) << 3);
            GLDS(Bh + go, &sBh[p][i * 512]);
        }
    };

    auto compute = [&](auto pc) {
        constexpr int p = decltype(pc)::value;
        bf16x8 ahf[MF], alf[MF], bhf[NF];
        #pragma unroll
        for (int m = 0; m < MF; ++m) {
            int rr = wr * WM + m * 16 + lr;
            int by = rr * 64 + ((lg ^ ((rr >> 1) & 3)) << 4);
            ahf[m] = *(const bf16x8*)((const char*)&sAh[p][0] + by);
            if constexpr (PLANES >= 2)
                alf[m] = *(const bf16x8*)((const char*)&sAl[p][0] + by);
        }
        #pragma unroll
        for (int n = 0; n < NF; ++n) {
            int rr = wc * WN + n * 16 + lr;
            int by = rr * 64 + ((lg ^ ((rr >> 1) & 3)) << 4);
            bhf[n] = *(const bf16x8*)((const char*)&sBh[p][0] + by);
        }
        #pragma unroll
        for (int m = 0; m < MF; ++m)
            #pragma unroll
            for (int n = 0; n < NF; ++n) {
                acc[m][n] = mfma16(ahf[m], bhf[n], acc[m][n]);
                if constexpr (PLANES >= 2)
                    acc[m][n] = mfma16(alf[m], bhf[n], acc[m][n]);
            }
    };

    stage(0, IC<0>{});
    int k0 = 32;
    for (; k0 + 32 < K; k0 += 64) {
        stage(k0, IC<1>{});
        vmwait<NLD>(); bar();
        compute(IC<0>{});
        bar();
        stage(k0 + 32, IC<0>{});
        vmwait<NLD>(); bar();
        compute(IC<1>{});
        bar();
    }
    stage(k0, IC<1>{});
    vmwait<NLD>(); bar();
    compute(IC<0>{});
    bar();
    vmwait<0>(); bar();
    compute(IC<1>{});

    #pragma unroll
    for (int m = 0; m < MF; ++m)
        #pragma unroll
        for (int n = 0; n < NF; ++n)
            #pragma unroll
            for (int r = 0; r < 4; ++r) {
                int grow = row0 + wr * WM + m * 16 + lg * 4 + r;
                int gcol = col0 + wc * WN + n * 16 + lr;
                float v = acc[m][n][r];
                if constexpr (EPIL == EP_SILU) {
                    float pv = __shfl_xor(v, 1, 64);   // partner column (g,u pair)
                    if (!(lr & 1)) {
                        float s = (v / (1.0f + expf(-v))) * pv;
                        size_t off = (size_t)grow * ldc + (gcol >> 1);
                        Ch[off] = (bf16_t)s;
                    }
                } else {
                    size_t off = (size_t)blockIdx.z * sC + (size_t)grow * ldc + gcol;
                    if constexpr (EPIL == EP_STORE) {
                        Cf[off] = v;
                    } else if constexpr (EPIL == EP_RESID) {
                        Cf[off] += v;
                    } else {  // EP_SPLIT
                        bf16_t hb = (bf16_t)v;
                        Ch[off] = hb;
                        Cl[off] = (bf16_t)(v - (float)hb);
                    }
                }
            }
}

// Logits GEMM: C[1024,32000] = A * B^T, 128x256 tile, 8 waves (2x4), hi-only.
// TRIPLE-buffered: stage chunk j+2 while computing j (2-phase latency cover);
// vmcnt(6) leaves 2 stages (3 loads each) in flight. 72 KB LDS, 2 blocks/CU.
__global__ __launch_bounds__(512, 4)
void gemm_logits(const bf16_t* __restrict__ Ah, const bf16_t* __restrict__ Bh,
                 float* __restrict__ Cf)
{
    constexpr int lda = 1024, ldb = 1024, ldc = 32000;
    __shared__ __align__(16) bf16_t sA[3][128 * 32], sB[3][256 * 32];

    const int gx = gridDim.x;
    int id = blockIdx.x + gx * blockIdx.y;
    {   // bijective XCD swizzle
        int nwg = gx * gridDim.y;
        int q = nwg >> 3, r = nwg & 7;
        int xcd = id & 7, ix = id >> 3;
        id = (xcd < r ? xcd * (q + 1) : r * (q + 1) + (xcd - r) * q) + ix;
    }
    const int bm = id % gx, bn = id / gx;
    const int row0 = bm * 128, col0 = bn * 256;

    const int tid = threadIdx.x, lane = tid & 63, wave = tid >> 6;
    const int lr = lane & 15, lg = lane >> 4;
    const int wr = wave >> 2, wc = wave & 3;   // 2x4 wave grid; WM=WN=64

    f32x4 acc[4][4];
    #pragma unroll
    for (int m = 0; m < 4; ++m)
        #pragma unroll
        for (int n = 0; n < 4; ++n) acc[m][n] = (f32x4){0.f, 0.f, 0.f, 0.f};

    auto stage = [&](int k0, int p) {
        {
            int i = wave;  // BM/16 = 8 row-groups, one per wave
            int s = i * 64 + lane, rr = s >> 2, c = s & 3;
            size_t go = (size_t)(row0 + rr) * lda + k0 + ((c ^ ((rr >> 1) & 3)) << 3);
            GLDS(Ah + go, &sA[p][i * 512]);
        }
        #pragma unroll
        for (int i = wave; i < 16; i += 8) {
            int s = i * 64 + lane, rr = s >> 2, c = s & 3;
            size_t go = (size_t)(col0 + rr) * ldb + k0 + ((c ^ ((rr >> 1) & 3)) << 3);
            GLDS(Bh + go, &sB[p][i * 512]);
        }
    };

    auto compute = [&](int p) {
        bf16x8 af[4], bf[4];
        #pragma unroll
        for (int m = 0; m < 4; ++m) {
            int rr = wr * 64 + m * 16 + lr;
            int by = rr * 64 + ((lg ^ ((rr >> 1) & 3)) << 4);
            af[m] = *(const bf16x8*)((const char*)&sA[p][0] + by);
        }
        #pragma unroll
        for (int n = 0; n < 4; ++n) {
            int rr = wc * 64 + n * 16 + lr;
            int by = rr * 64 + ((lg ^ ((rr >> 1) & 3)) << 4);
            bf[n] = *(const bf16x8*)((const char*)&sB[p][0] + by);
        }
        #pragma unroll
        for (int m = 0; m < 4; ++m)
            #pragma unroll
            for (int n = 0; n < 4; ++n)
                acc[m][n] = mfma16(af[m], bf[n], acc[m][n]);
    };

    stage(0, 0);
    stage(32, 1);
    for (int j = 0; j < 30; ++j) {
        stage(32 * (j + 2), (j + 2) % 3);
        vmwait<6>(); bar();     // stage j landed; j+1, j+2 stay in flight
        compute(j % 3);
        bar();                  // protect buf before next phase's stage
    }
    vmwait<3>(); bar();
    compute(0);                 // chunk 30
    vmwait<0>(); bar();
    compute(1);                 // chunk 31

    #pragma unroll
    for (int m = 0; m < 4; ++m)
        #pragma unroll
        for (int n = 0; n < 4; ++n)
            #pragma unroll
            for (int r = 0; r < 4; ++r) {
                int grow = row0 + wr * 64 + m * 16 + lg * 4 + r;
                int gcol = col0 + wc * 64 + n * 16 + lr;
                Cf[(size_t)grow * ldc + gcol] = acc[m][n][r];
            }
}

// weight-pack body: b2 in [0,4096); handles 4 chunks of 1024 f32 each.
// wq|wk|wv|wo -> wAh [4096x1024]; wg|wu -> wGUh INTERLEAVED; wd -> wdh.
static __device__ __forceinline__ void wsplit_body(
    int b2, int tid,
    const float* wq, const float* wk, const float* wv, const float* wo,
    const float* wg, const float* wu, const float* wd,
    bf16_t* wAh, bf16_t* wGUh, bf16_t* wdh)
{
    #pragma unroll
    for (int k = 0; k < 4; ++k) {
        int b = b2 * 4 + k;
        const float* src;
        bf16_t* dst;
        size_t so, doff;
        if (b < 4096) {
            src = b < 1024 ? wq : b < 2048 ? wk : b < 3072 ? wv : wo;
            so = (size_t)(b & 1023) * 256 + tid;
            doff = (size_t)b * 256 + tid;
            dst = wAh;
        } else if (b < 12288) {
            int bb = b - 4096;
            int row = bb < 4096 ? 2 * bb : 2 * (bb - 4096) + 1;
            src = bb < 4096 ? wg : wu;
            so = (size_t)(bb & 4095) * 256 + tid;
            doff = (size_t)row * 256 + tid;
            dst = wGUh;
        } else {
            src = wd;
            so = (size_t)(b - 12288) * 256 + tid;
            doff = so;
            dst = wdh;
        }
        f32x4 v = ((const f32x4*)src)[so];
        bf16x4 hv;
        #pragma unroll
        for (int j = 0; j < 4; ++j) hv[j] = (bf16_t)v[j];
        ((bf16x4*)dst)[doff] = hv;
    }
}

// blocks 0-1023: h += 4 split-K partials then RMS-norm -> hi plane.
// blocks 1024-5119: pack NEXT layer's weights (skipped if wq == null).
__global__ __launch_bounds__(256)
void reduce_rms_wsplit(const float* __restrict__ p, float* __restrict__ h,
                       const float* __restrict__ w, bf16_t* __restrict__ outh,
                       const float* wq, const float* wk, const float* wv,
                       const float* wo, const float* wg, const float* wu,
                       const float* wd, bf16_t* wAh, bf16_t* wGUh, bf16_t* wdh)
{
    int blk = blockIdx.x, tid = threadIdx.x;
    if (blk >= 1024) {
        if (wq) wsplit_body(blk - 1024, tid, wq, wk, wv, wo, wg, wu, wd,
                            wAh, wGUh, wdh);
        return;
    }
    size_t i = (size_t)blk * 256 + tid;
    const size_t S = (1024 * 1024) / 4;
    f32x4 a = ((const f32x4*)p)[i];
    f32x4 b = ((const f32x4*)p)[i + S];
    f32x4 c = ((const f32x4*)p)[i + 2 * S];
    f32x4 d = ((const f32x4*)p)[i + 3 * S];
    f32x4 hv = ((const f32x4*)h)[i];
    #pragma unroll
    for (int j = 0; j < 4; ++j) hv[j] += (a[j] + b[j]) + (c[j] + d[j]);
    ((f32x4*)h)[i] = hv;

    float ss = hv[0]*hv[0] + hv[1]*hv[1] + hv[2]*hv[2] + hv[3]*hv[3];
    #pragma unroll
    for (int m = 1; m < 64; m <<= 1) ss += __shfl_xor(ss, m, 64);
    __shared__ float red[4];
    if ((tid & 63) == 0) red[tid >> 6] = ss;
    __syncthreads();
    float tot = red[0] + red[1] + red[2] + red[3];
    float inv = rsqrtf(tot * (1.0f / 1024.0f) + RMS_EPS);
    f32x4 wt4 = *(const f32x4*)(w + tid * 4);
    bf16x4 hv4;
    #pragma unroll
    for (int j = 0; j < 4; ++j) hv4[j] = (bf16_t)(hv[j] * inv * wt4[j]);
    ((bf16x4*)outh)[i] = hv4;
}

// blocks 0-1023: gather embed row, write fp32 h, RMS-norm -> hi.
// blocks 1024-5119: pack layer-0 weights.
__global__ __launch_bounds__(256)
void gather_rms_wsplit(const int* __restrict__ ids, const float* __restrict__ embed,
                       const float* __restrict__ w, float* __restrict__ h,
                       bf16_t* __restrict__ outh,
                       const float* wq, const float* wk, const float* wv,
                       const float* wo, const float* wg, const float* wu,
                       const float* wd, bf16_t* wAh, bf16_t* wGUh, bf16_t* wdh)
{
    int blk = blockIdx.x, tid = threadIdx.x;
    if (blk >= 1024) {
        wsplit_body(blk - 1024, tid, wq, wk, wv, wo, wg, wu, wd, wAh, wGUh, wdh);
        return;
    }
    int row = ids[blk];
    f32x4 v = ((const f32x4*)(embed + (size_t)row * 1024))[tid];
    ((f32x4*)(h + (size_t)blk * 1024))[tid] = v;

    float ss = v[0]*v[0] + v[1]*v[1] + v[2]*v[2] + v[3]*v[3];
    #pragma unroll
    for (int m = 1; m < 64; m <<= 1) ss += __shfl_xor(ss, m, 64);
    __shared__ float red[4];
    if ((tid & 63) == 0) red[tid >> 6] = ss;
    __syncthreads();
    float tot = red[0] + red[1] + red[2] + red[3];
    float inv = rsqrtf(tot * (1.0f / 1024.0f) + RMS_EPS);
    f32x4 wt4 = *(const f32x4*)(w + tid * 4);
    bf16x4 hv;
    #pragma unroll
    for (int j = 0; j < 4; ++j) hv[j] = (bf16_t)(v[j] * inv * wt4[j]);
    ((bf16x4*)outh)[(size_t)blk * 256 + tid] = hv;
}

// Flash attention: block (qb,hh) handles q-chunk qb (32 rows), KB=64 keys/tile.
// 512 blocks -> >=2 blocks/CU (36 KB LDS) for latency hiding. 2 waves.
// Q,K hi-only; V hi+lo; softcap+causal+online softmax fp32; P hi/lo via
// per-wave LDS; 3-term P.V. O written hi-only.
__global__ __launch_bounds__(128, 2)
void flash_attn(const bf16_t* __restrict__ qkvh,
                const bf16_t* __restrict__ vTh, const bf16_t* __restrict__ vTl,
                bf16_t* __restrict__ oh)
{
    __shared__ __align__(16) bf16_t sQ[32*64], sK[64*64], sVh[64*64], sVl[64*64];
    __shared__ __align__(16) bf16_t sPh[32*64], sPl[32*64];

    const int q0 = blockIdx.x * 32;
    const int hh = blockIdx.y;
    const int tid = threadIdx.x, lane = tid & 63, w = tid >> 6;
    const int lr = lane & 15, lg = lane >> 4;

    #pragma unroll
    for (int ii = 0; ii < 2; ++ii) {
        int r0 = w * 16 + ii * 8;
        int r  = r0 + (lane >> 3);
        int i  = lane & 7;
        GLDS(qkvh + (size_t)(q0 + r) * 3072 + hh * 64 + ((i ^ (r & 7)) << 3),
             sQ + r0 * 64);
    }
    __syncthreads();

    bf16x8 qa[2];
    #pragma unroll
    for (int ks = 0; ks < 2; ++ks) {
        int r = w * 16 + lr;
        qa[ks] = *(const bf16x8*)((const char*)sQ + r * 128 +
                                  ((((ks << 2) | lg) ^ (r & 7)) << 4));
    }

    f32x4 o_acc[4];
    #pragma unroll
    for (int n = 0; n < 4; ++n) o_acc[n] = (f32x4){0.f, 0.f, 0.f, 0.f};
    float m_run[4] = {-1e30f, -1e30f, -1e30f, -1e30f};
    float l_run[4] = {0.f, 0.f, 0.f, 0.f};

    const int ntiles = ((q0 + 31) >> 6) + 1;
    for (int t = 0; t < ntiles; ++t) {
        const int kv0 = t * 64;
        #pragma unroll
        for (int ii = 0; ii < 4; ++ii) {
            int r0 = w * 32 + ii * 8;
            int r  = r0 + (lane >> 3);
            int i  = lane & 7;
            GLDS(qkvh + (size_t)(kv0 + r) * 3072 + 1024 + hh * 64 + ((i ^ (r & 7)) << 3),
                 sK + r0 * 64);
            GLDS(vTh + (size_t)(hh * 64 + r) * 1024 + kv0 + ((i ^ (r & 7)) << 3),
                 sVh + r0 * 64);
            GLDS(vTl + (size_t)(hh * 64 + r) * 1024 + kv0 + ((i ^ (r & 7)) << 3),
                 sVl + r0 * 64);
        }
        __syncthreads();

        f32x4 s_acc[4];
        #pragma unroll
        for (int n = 0; n < 4; ++n) s_acc[n] = (f32x4){0.f, 0.f, 0.f, 0.f};
        #pragma unroll
        for (int ks = 0; ks < 2; ++ks)
            #pragma unroll
            for (int n = 0; n < 4; ++n) {
                int r = n * 16 + lr;
                bf16x8 kb = *(const bf16x8*)((const char*)sK + r * 128 +
                                             ((((ks << 2) | lg) ^ (r & 7)) << 4));
                s_acc[n] = mfma16(qa[ks], kb, s_acc[n]);
            }

        #pragma unroll
        for (int j = 0; j < 4; ++j) {
            int qr = q0 + w * 16 + lg * 4 + j;
            float p[4];
            float mx = -1e30f;
            #pragma unroll
            for (int n = 0; n < 4; ++n) {
                float v = s_acc[n][j] * 0.125f;
                v = 50.f * tanhf(v * 0.02f);
                int key = kv0 + n * 16 + lr;
                if (key > qr) v = -1e30f;
                p[n] = v;
                mx = fmaxf(mx, v);
            }
            #pragma unroll
            for (int m = 1; m < 16; m <<= 1) mx = fmaxf(mx, __shfl_xor(mx, m, 64));
            float mn = fmaxf(m_run[j], mx);
            float ef = __expf(m_run[j] - mn);
            m_run[j] = mn;
            float rs = 0.f;
            #pragma unroll
            for (int n = 0; n < 4; ++n) {
                float e = expf(p[n] - mn);
                p[n] = e;
                rs += e;
            }
            #pragma unroll
            for (int m = 1; m < 16; m <<= 1) rs += __shfl_xor(rs, m, 64);
            l_run[j] = l_run[j] * ef + rs;
            #pragma unroll
            for (int n = 0; n < 4; ++n) o_acc[n][j] *= ef;
            int r = w * 16 + lg * 4 + j;
            #pragma unroll
            for (int n = 0; n < 4; ++n) {
                int c = n * 16 + lr;
                int byo = r * 128 + ((((c >> 3) ^ (r & 7)) << 4)) + ((c & 7) << 1);
                bf16_t hb = (bf16_t)p[n];
                *(bf16_t*)((char*)sPh + byo) = hb;
                *(bf16_t*)((char*)sPl + byo) = (bf16_t)(p[n] - (float)hb);
            }
        }

        #pragma unroll
        for (int ks = 0; ks < 2; ++ks) {
            int pr = w * 16 + lr;
            int pby = pr * 128 + ((((ks << 2) | lg) ^ (pr & 7)) << 4);
            bf16x8 pa  = *(const bf16x8*)((const char*)sPh + pby);
            bf16x8 pl_ = *(const bf16x8*)((const char*)sPl + pby);
            #pragma unroll
            for (int n = 0; n < 4; ++n) {
                int vr = n * 16 + lr;
                int vby = vr * 128 + ((((ks << 2) | lg) ^ (vr & 7)) << 4);
                bf16x8 vhf = *(const bf16x8*)((const char*)sVh + vby);
                bf16x8 vlf = *(const bf16x8*)((const char*)sVl + vby);
                o_acc[n] = mfma16(pa,  vhf, o_acc[n]);
                o_acc[n] = mfma16(pl_, vhf, o_acc[n]);
                o_acc[n] = mfma16(pa,  vlf, o_acc[n]);
            }
        }
        __syncthreads();
    }

    #pragma unroll
    for (int j = 0; j < 4; ++j) {
        float inv = 1.0f / l_run[j];
        int qr = q0 + w * 16 + lg * 4 + j;
        #pragma unroll
        for (int n = 0; n < 4; ++n) {
            size_t off = (size_t)qr * 1024 + hh * 64 + n * 16 + lr;
            oh[off] = (bf16_t)(o_acc[n][j] * inv);
        }
    }
}

__global__ __launch_bounds__(256)
void split_kernel(const float* __restrict__ src, bf16_t* __restrict__ hi)
{
    size_t i = (size_t)blockIdx.x * 256 + threadIdx.x;
    f32x4 v = ((const f32x4*)src)[i];
    bf16x4 hv;
    #pragma unroll
    for (int j = 0; j < 4; ++j) hv[j] = (bf16_t)v[j];
    ((bf16x4*)hi)[i] = hv;
}

__global__ __launch_bounds__(256)
void rmsnorm_split(const float* __restrict__ in, const float* __restrict__ w,
                   bf16_t* __restrict__ outh)
{
    int row = blockIdx.x, tid = threadIdx.x;
    f32x4 v = *(const f32x4*)(in + (size_t)row * 1024 + tid * 4);
    float ss = v[0]*v[0] + v[1]*v[1] + v[2]*v[2] + v[3]*v[3];
    #pragma unroll
    for (int m = 1; m < 64; m <<= 1) ss += __shfl_xor(ss, m, 64);
    __shared__ float red[4];
    if ((tid & 63) == 0) red[tid >> 6] = ss;
    __syncthreads();
    float tot = red[0] + red[1] + red[2] + red[3];
    float inv = rsqrtf(tot * (1.0f / 1024.0f) + RMS_EPS);
    f32x4 wt4 = *(const f32x4*)(w + tid * 4);
    bf16x4 hv;
    #pragma unroll
    for (int j = 0; j < 4; ++j) hv[j] = (bf16_t)(v[j] * inv * wt4[j]);
    ((bf16x4*)outh)[(size_t)row * 256 + tid] = hv;
}

// Merged: blocks 0-1023  = per-(t,head) RMS(Dh=64)+RoPE on packed qkv [1024][3072]
//         blocks 1024-3071 = v (cols 2048-3071) -> vT [1024][1024], hi/lo planes.
// Reference quirk: rotation angle = head_index * freq (cos[:n], n = H).
__global__ __launch_bounds__(256)
void rope_transpose(bf16_t* __restrict__ qkvh, bf16_t* __restrict__ qkvl,
                    const float* __restrict__ qn, const float* __restrict__ kn,
                    bf16_t* __restrict__ vTh, bf16_t* __restrict__ vTl)
{
    __shared__ bf16_t tile[32][33];
    int b = blockIdx.x;
    if (b >= 1024) {
        int t2 = b - 1024;
        int z = t2 >> 10, rem = t2 & 1023;
        const bf16_t* in = z ? qkvl : qkvh;
        bf16_t* out      = z ? vTl : vTh;
        int bx = (rem & 31) * 32, by = (rem >> 5) * 32;
        int r = threadIdx.x >> 5, c = threadIdx.x & 31;
        #pragma unroll
        for (int rr = r; rr < 32; rr += 8)
            tile[rr][c] = in[(size_t)(by + rr) * 3072 + 2048 + bx + c];
        __syncthreads();
        #pragma unroll
        for (int rr = r; rr < 32; rr += 8)
            out[(size_t)(bx + rr) * 1024 + by + c] = tile[c][rr];
        return;
    }

    int t = b, tid = threadIdx.x;
    int hh = tid >> 4;
    int i  = (tid & 15) * 4;
    size_t qb = ((size_t)t * 3072 + hh * 64 + i) >> 2;
    size_t kb = qb + (1024 >> 2);

    int p0 = i >> 1;
    float f0 = powf(10000.f, -(float)p0 / 32.f);
    float f1 = powf(10000.f, -(float)(p0 + 1) / 32.f);
    float a0 = (float)hh * f0, a1 = (float)hh * f1;
    float c0 = cosf(a0), s0 = sinf(a0);
    float c1 = cosf(a1), s1 = sinf(a1);

    f32x4 qw = *(const f32x4*)(qn + i);
    f32x4 kw = *(const f32x4*)(kn + i);

    {
        bf16x4 h4 = ((const bf16x4*)qkvh)[qb], l4 = ((const bf16x4*)qkvl)[qb];
        float x[4];
        #pragma unroll
        for (int j = 0; j < 4; ++j) x[j] = (float)h4[j] + (float)l4[j];
        float ss = x[0]*x[0] + x[1]*x[1] + x[2]*x[2] + x[3]*x[3];
        #pragma unroll
        for (int m = 1; m < 16; m <<= 1) ss += __shfl_xor(ss, m, 64);
        float inv = rsqrtf(ss * (1.0f / 64.0f) + RMS_EPS);
        float x0 = x[0]*inv*qw[0], x1 = x[1]*inv*qw[1];
        float x2 = x[2]*inv*qw[2], x3 = x[3]*inv*qw[3];
        bf16x4 o4;
        o4[0] = (bf16_t)(x0*c0 - x1*s0);  o4[1] = (bf16_t)(x0*s0 + x1*c0);
        o4[2] = (bf16_t)(x2*c1 - x3*s1);  o4[3] = (bf16_t)(x2*s1 + x3*c1);
        ((bf16x4*)qkvh)[qb] = o4;
    }
    {
        bf16x4 h4 = ((const bf16x4*)qkvh)[kb], l4 = ((const bf16x4*)qkvl)[kb];
        float x[4];
        #pragma unroll
        for (int j = 0; j < 4; ++j) x[j] = (float)h4[j] + (float)l4[j];
        float ss = x[0]*x[0] + x[1]*x[1] + x[2]*x[2] + x[3]*x[3];
        #pragma unroll
        for (int m = 1; m < 16; m <<= 1) ss += __shfl_xor(ss, m, 64);
        float inv = rsqrtf(ss * (1.0f / 64.0f) + RMS_EPS);
        float x0 = x[0]*inv*kw[0], x1 = x[1]*inv*kw[1];
        float x2 = x[2]*inv*kw[2], x3 = x[3]*inv*kw[3];
        bf16x4 o4;
        o4[0] = (bf16_t)(x0*c0 - x1*s0);  o4[1] = (bf16_t)(x0*s0 + x1*c0);
        o4[2] = (bf16_t)(x2*c1 - x3*s1);  o4[3] = (bf16_t)(x2*s1 + x3*c1);
        ((bf16x4*)qkvh)[kb] = o4;
    }
}

extern "C" void kernel_launch(void* const* d_in, const int* in_sizes, int n_in,
                              void* d_out, int out_size, void* d_ws, size_t ws_size,
                              hipStream_t stream)
{
    (void)in_sizes; (void)n_in; (void)out_size; (void)ws_size;
    const int*   x_ids = (const int*)  d_in[0];
    const float* embed = (const float*)d_in[1];
    const float* ln1   = (const float*)d_in[2];
    const float* Wq    = (const float*)d_in[3];
    const float* Wk    = (const float*)d_in[4];
    const float* Wv    = (const float*)d_in[5];
    const float* Wo    = (const float*)d_in[6];
    const float* qn    = (const float*)d_in[7];
    const float* kn    = (const float*)d_in[8];
    const float* ln2   = (const float*)d_in[9];
    const float* Wg    = (const float*)d_in[10];
    const float* Wu    = (const float*)d_in[11];
    const float* Wd    = (const float*)d_in[12];
    const float* lnout = (const float*)d_in[13];
    float* out = (float*)d_out;

    char* ws = (char*)d_ws;
    const size_t MB = 1 << 20;
    float*  h    = (float*) (ws +   0 * MB);  // 4 MB fp32 residual
    bf16_t* hnh  = (bf16_t*)(ws +   4 * MB);
    bf16_t* qkvh = (bf16_t*)(ws +   8 * MB);  // 6 MB [1024][3072]
    bf16_t* qkvl = (bf16_t*)(ws +  14 * MB);
    bf16_t* vTh  = (bf16_t*)(ws +  20 * MB);
    bf16_t* vTl  = (bf16_t*)(ws +  22 * MB);
    bf16_t* oh   = (bf16_t*)(ws +  24 * MB);
    bf16_t* wAh  = (bf16_t*)(ws +  28 * MB);  //  8 MB [4096][1024] hi-only
    bf16_t* wGUh = (bf16_t*)(ws +  36 * MB);  // 16 MB [8192][1024] interleaved hi
    bf16_t* wdh  = (bf16_t*)(ws +  52 * MB);  //  8 MB [1024][4096] hi-only
    bf16_t* silh = (bf16_t*)(ws +  60 * MB);  //  8 MB [1024][4096]
    float*  wdp  = (float*) (ws +  68 * MB);  // 16 MB split-K partials [4][1024][1024]
    bf16_t* eh   = (bf16_t*)(ws +  84 * MB);  // 62.5 MB embed hi (high-water ~147 MB)

    const long long M1 = 1024 * 1024;

    gather_rms_wsplit<<<5120, 256, 0, stream>>>(
        x_ids, embed, ln1, h, hnh,
        Wq, Wk, Wv, Wo, Wg, Wu, Wd, wAh, wGUh, wdh);

    for (int l = 0; l < 6; ++l) {
        // fused QKV (1-plane bf16): [1024][3072] = hn @ wA[0:3072]^T
        gemm_bf16<64,128,2,2,1,EP_SPLIT><<<dim3(16,24),256,0,stream>>>(
            hnh, nullptr, wAh, nullptr, qkvh, qkvl, 1024, 1024, 1024, 3072, 0);

        rope_transpose<<<3072, 256, 0, stream>>>(qkvh, qkvl, qn + l * 64, kn + l * 64,
                                                 vTh, vTl);

        // fused scores+softcap+mask+softmax+PV; O hi-only
        flash_attn<<<dim3(32,16), 128, 0, stream>>>(qkvh, vTh, vTl, oh);

        // Wo residual (1-plane bf16, 64^2 tiles)
        gemm_bf16<64,64,2,2,1,EP_RESID><<<dim3(16,16),256,0,stream>>>(
            oh, nullptr, wAh + 3 * M1, h, nullptr, nullptr, 1024, 1024, 1024, 1024, 0);

        rmsnorm_split<<<1024, 256, 0, stream>>>(h, ln2 + l * 1024, hnh);

        // fused gate+up+silu (1-plane, 128x256 tile, 8 waves): writes sil hi
        gemm_bf16<128,256,2,4,1,EP_SILU><<<dim3(8,32),512,0,stream>>>(
            hnh, nullptr, wGUh, nullptr, silh, nullptr, 1024, 1024, 1024, 4096, 0);

        // down-proj: split-K x4 (1-plane bf16) -> partials
        gemm_bf16<128,128,2,2,1,EP_STORE><<<dim3(8,8,4),256,0,stream>>>(
            silh, nullptr, wdh, wdp, nullptr, nullptr, 1024, 4096, 4096, 1024, M1);

        // reduce partials into h + next pre-norm + pack next layer's weights
        const float* wnext = (l < 5) ? (ln1 + (l + 1) * 1024) : lnout;
        if (l < 5) {
            reduce_rms_wsplit<<<5120, 256, 0, stream>>>(
                wdp, h, wnext, hnh,
                Wq + (size_t)(l+1) * M1, Wk + (size_t)(l+1) * M1,
                Wv + (size_t)(l+1) * M1, Wo + (size_t)(l+1) * M1,
                Wg + (size_t)(l+1) * 4 * M1, Wu + (size_t)(l+1) * 4 * M1,
                Wd + (size_t)(l+1) * 4 * M1, wAh, wGUh, wdh);
        } else {
            reduce_rms_wsplit<<<1024, 256, 0, stream>>>(
                wdp, h, wnext, hnh,
                nullptr, nullptr, nullptr, nullptr, nullptr, nullptr, nullptr,
                wAh, wGUh, wdh);
        }
    }

    split_kernel<<<32000, 256, 0, stream>>>(embed, eh);
    // logits (1-plane, 128x256, 3-buffer deep pipeline): [1024][32000]
    gemm_logits<<<dim3(8,125), 512, 0, stream>>>(hnh, eh, out);
}